// Round 21
// baseline (440.873 us; speedup 1.0000x reference)
//
#include <hip/hip_runtime.h>
#include <hip/hip_bf16.h>
#include <math.h>

// Problem constants
#define BB 2
#define CC 3
#define HH 512
#define WW 512
#define GG 64
#define LL 4096
#define FDIM 128
#define PDIM 192   // C*K*K
#define MDIM 320   // PDIM + FDIM
#define DDIM 256
#define TOPK 16
#define RHID 128
#define SCALE (1.0f/16.0f)   // 1/(sqrt(256)*TEMP)

#define NQ2 8      // queries per topk block
#define CHK3 1024  // key chunk (4 contiguous keys per thread, 256 threads)
#define KB 2       // key partials
#define TOKG 16    // tokens per gemm block
#define TKT 32     // keys per transpose-gather block
#define NQM 4      // queries per mlp block
#define KFP 129    // kf row stride (odd: conflict-free)

// ---------------- kernel 2: fused build (img rows + out copy + feat transpose) ----
__global__ __launch_bounds__(256) void k_build2(const float* __restrict__ img,
        const float* __restrict__ feat, float* __restrict__ match,
        float* __restrict__ out) {
    int b = blockIdx.y;
    int l0 = blockIdx.x * 64;         // tokens l0..l0+63, gy = l0>>6
    int gy = l0 >> 6;
    int t = threadIdx.x;

    const float4* im4 = (const float4*)img;
    float4* out4 = (float4*)out;
    for (int idx = t; idx < 24 * 128; idx += 256) {   // 128 float4 per row
        int r = idx >> 7;             // 0..23 = c*8+ky
        int x4 = idx & 127;
        int c = r >> 3, ky = r & 7;
        size_t gofs = (((size_t)(b * CC + c) * HH + gy * 8 + ky) * WW >> 2) + x4;
        float4 v = im4[gofs];
        out4[gofs] = v;               // fused baseline copy
        int gx = x4 >> 1;
        int kx = (x4 & 1) * 4;
        *(float4*)&match[(size_t)(b * LL + l0 + gx) * MDIM + c * 64 + ky * 8 + kx] = v;
    }

    __shared__ float tf[FDIM][65];    // padded: conflict-free transpose
    for (int idx = t; idx < FDIM * 64; idx += 256) {
        int f = idx >> 6, ll = idx & 63;
        tf[f][ll] = feat[((size_t)(b * FDIM + f) << 12) + l0 + ll];
    }
    __syncthreads();
    for (int idx = t; idx < 64 * FDIM; idx += 256) {
        int ll = idx >> 7, f = idx & 127;
        match[(size_t)(b * LL + l0 + ll) * MDIM + PDIM + f] = tf[f][ll];
    }
}

// ---------------- kernel 3: compact masked queries AND valid keys ----------------
__global__ void k_compact(const int* __restrict__ mask, int* __restrict__ qlist,
                          int* __restrict__ klist, int* __restrict__ counts) {
    int bl = blockIdx.x * blockDim.x + threadIdx.x;
    if (bl >= BB * LL) return;
    int b = bl >> 12, l = bl & (LL - 1);
    if (mask[bl] > 0) {
        int s = atomicAdd(&counts[b], 1);          // qcnt
        qlist[b * LL + s] = l;
    } else {
        int s = atomicAdd(&counts[BB + b], 1);     // kcnt
        klist[b * LL + s] = l;
    }
}

// ---------------- kernel 4: fused token GEMM (desc + [qf|kf]), TOKG=16 ----------
__global__ __launch_bounds__(256) void k_gemm2(const float* __restrict__ match,
        const float* __restrict__ Wd, const float* __restrict__ Wq,
        const float* __restrict__ Wk,
        float* __restrict__ desc, float* __restrict__ qkf) {
    __shared__ float sm[TOKG * MDIM];   // 20 KB
    int base = blockIdx.x * TOKG;
    int t = threadIdx.x;
    for (int i = t; i < TOKG * MDIM; i += 256) sm[i] = match[(size_t)base * MDIM + i];
    __syncthreads();
    const float4* sm4 = (const float4*)sm;
    const float* W1p = (t < 128) ? Wq : Wk;
    int c1 = t & 127;
    float acc0[TOKG], acc1[TOKG];
#pragma unroll
    for (int tt = 0; tt < TOKG; ++tt) { acc0[tt] = 0.f; acc1[tt] = 0.f; }
    for (int m = 0; m < MDIM; m += 4) {
        float w00 = Wd[(m+0)*DDIM + t], w01 = Wd[(m+1)*DDIM + t];
        float w02 = Wd[(m+2)*DDIM + t], w03 = Wd[(m+3)*DDIM + t];
        float w10 = W1p[(m+0)*RHID + c1], w11 = W1p[(m+1)*RHID + c1];
        float w12 = W1p[(m+2)*RHID + c1], w13 = W1p[(m+3)*RHID + c1];
        int mg = m >> 2;
#pragma unroll
        for (int tt = 0; tt < TOKG; ++tt) {
            float4 s = sm4[tt * (MDIM/4) + mg];
            acc0[tt] += s.x*w00 + s.y*w01 + s.z*w02 + s.w*w03;
            acc1[tt] += s.x*w10 + s.y*w11 + s.z*w12 + s.w*w13;
        }
    }
#pragma unroll
    for (int tt = 0; tt < TOKG; ++tt) {
        desc[(size_t)(base+tt)*DDIM + t] = acc0[tt];
        qkf [(size_t)(base+tt)*DDIM + t] = acc1[tt];
    }
}

// ---------------- kernel 5: gather valid keys, TRANSPOSED: kdesc_t[d][kk] ----
__global__ __launch_bounds__(256) void k_gatherkT(const float* __restrict__ desc,
        const int* __restrict__ klist, const int* __restrict__ counts,
        float* __restrict__ kdesc_t) {
    int b = blockIdx.y;
    int vcnt = counts[BB + b];
    int kt = blockIdx.x * TKT;
    if (kt >= vcnt) return;
    int nk = min(TKT, vcnt - kt);
    __shared__ float sm[TKT][DDIM + 1];   // +1 pad: transpose-read conflict-free
    int t = threadIdx.x;
    for (int r = (t >> 6); r < nk; r += 4) {
        int src = klist[b * LL + kt + r];
        const float4* s = (const float4*)(desc + ((size_t)b * LL + src) * DDIM);
        float4 v = s[t & 63];
        int d0 = (t & 63) * 4;
        sm[r][d0] = v.x; sm[r][d0+1] = v.y; sm[r][d0+2] = v.z; sm[r][d0+3] = v.w;
    }
    __syncthreads();
    float* outb = kdesc_t + (size_t)b * DDIM * LL;
    int kk = t & 31;
    for (int d = (t >> 5); d < DDIM; d += 8) {
        if (kk < nk) outb[(size_t)d * LL + kt + kk] = sm[kk][d];
    }
}

// ---------------- kernel 6: fused logits + wave-register top-16 ----------------
// r13 structure + explicit depth-1 software prefetch of the 4 kx key streams.
__global__ __launch_bounds__(256, 4) void k_topk4(const float* __restrict__ desc,
        const float* __restrict__ kdt,
        const int* __restrict__ qlist, const int* __restrict__ klist,
        const int* __restrict__ counts,
        float* __restrict__ tval2, int* __restrict__ tidx2) {
    int b = blockIdx.z;
    int kb = blockIdx.y;
    int cnt  = counts[b];
    int vcnt = counts[BB + b];
    int i0 = blockIdx.x * NQ2;
    if (i0 >= cnt) return;
    int nq = min(NQ2, cnt - i0);
    int t = threadIdx.x;
    int lane = t & 63, w = t >> 6;

    __shared__ float sq[NQ2 * DDIM];     // 8 KB
    __shared__ float lc[NQ2][CHK3];      // 32 KB  (40 KB total -> 4 blocks/CU)

#pragma unroll
    for (int qi = 0; qi < NQ2; ++qi) {
        int qtok = qlist[b * LL + i0 + min(qi, nq - 1)];
        sq[qi * DDIM + t] = desc[((size_t)b * LL + qtok) * DDIM + t];
    }
    __syncthreads();

    int khalf = (vcnt + 1) >> 1;
    int kstart = kb * khalf;
    int kend = min(vcnt, kstart + khalf);

    float tva = -INFINITY, tvb = -INFINITY;
    int   tia = 0x7fffffff, tib = 0x7fffffff;

    const float4* sq4 = (const float4*)sq;
    const float* kbase = kdt + (size_t)b * DDIM * LL;
    const int* klb = klist + b * LL;

    int nch = (kend > kstart) ? (kend - kstart + CHK3 - 1) / CHK3 : 0;
    for (int ch = 0; ch < nch; ++ch) {
        int base = kstart + ch * CHK3;
        int k0 = base + 4 * t;            // 4 contiguous keys
        int k0c = min(k0, LL - 4);        // stay inside the d-row

        float acc[NQ2][4];
#pragma unroll
        for (int qi = 0; qi < NQ2; ++qi)
#pragma unroll
            for (int r = 0; r < 4; ++r) acc[qi][r] = 0.f;

        // software pipeline: kx for db+1 loaded while computing db
        float4 nkx0 = *(const float4*)(kbase + (size_t)0 * LL + k0c);
        float4 nkx1 = *(const float4*)(kbase + (size_t)1 * LL + k0c);
        float4 nkx2 = *(const float4*)(kbase + (size_t)2 * LL + k0c);
        float4 nkx3 = *(const float4*)(kbase + (size_t)3 * LL + k0c);
        for (int db = 0; db < DDIM / 4; ++db) {
            float4 kx0 = nkx0, kx1 = nkx1, kx2 = nkx2, kx3 = nkx3;
            if (db + 1 < DDIM / 4) {
                const float* nrow = kbase + (size_t)((db + 1) * 4) * LL;
                nkx0 = *(const float4*)(nrow + 0 * LL + k0c);
                nkx1 = *(const float4*)(nrow + 1 * LL + k0c);
                nkx2 = *(const float4*)(nrow + 2 * LL + k0c);
                nkx3 = *(const float4*)(nrow + 3 * LL + k0c);
            }
#pragma unroll
            for (int qi = 0; qi < NQ2; ++qi) {
                float4 qv = sq4[qi * (DDIM/4) + db];
                acc[qi][0] += qv.x*kx0.x + qv.y*kx1.x + qv.z*kx2.x + qv.w*kx3.x;
                acc[qi][1] += qv.x*kx0.y + qv.y*kx1.y + qv.z*kx2.y + qv.w*kx3.y;
                acc[qi][2] += qv.x*kx0.z + qv.y*kx1.z + qv.z*kx2.z + qv.w*kx3.z;
                acc[qi][3] += qv.x*kx0.w + qv.y*kx1.w + qv.z*kx2.w + qv.w*kx3.w;
            }
        }
        __syncthreads();   // previous selection done reading lc
#pragma unroll
        for (int qi = 0; qi < NQ2; ++qi) {
            float4 o;
            o.x = (k0 + 0 < kend) ? acc[qi][0] * SCALE : -INFINITY;
            o.y = (k0 + 1 < kend) ? acc[qi][1] * SCALE : -INFINITY;
            o.z = (k0 + 2 < kend) ? acc[qi][2] * SCALE : -INFINITY;
            o.w = (k0 + 3 < kend) ? acc[qi][3] * SCALE : -INFINITY;
            *(float4*)&lc[qi][4 * t] = o;
        }
        __syncthreads();

        // merged selection: one pass over j-groups; klist loaded once, both
        // queries (2w, 2w+1) processed from the same loads (r13-proven).
        for (int j = 0; j < CHK3 / 64; ++j) {
            int p = j * 64 + lane;
            int gk = base + p;
            int kidx = (gk < kend) ? klb[gk] : 0x7fffffff;
            float va = lc[2 * w + 0][p];
            float vb = lc[2 * w + 1][p];
            {   // query A
                float thrv = __shfl(tva, 15);
                int   thri = __shfl(tia, 15);
                bool pass = (va > thrv) || (va == thrv && kidx < thri);
                unsigned long long mball = __ballot(pass);
                while (mball) {
                    int src = __ffsll(mball) - 1;
                    float vv = __shfl(va, src);
                    int   ii = __shfl(kidx, src);
                    bool beat = (vv > tva) || (vv == tva && ii < tia);
                    float pv = __shfl_up(tva, 1);
                    int   pi = __shfl_up(tia, 1);
                    bool beatp = (lane > 0) && ((vv > pv) || (vv == pv && ii < pi));
                    if (lane < 16 && beat) { tva = beatp ? pv : vv; tia = beatp ? pi : ii; }
                    mball &= mball - 1;
                    if (mball) {
                        float t15 = __shfl(tva, 15);
                        int   i15 = __shfl(tia, 15);
                        bool still = (va > t15) || (va == t15 && kidx < i15);
                        mball &= __ballot(still);
                    }
                }
            }
            {   // query B
                float thrv = __shfl(tvb, 15);
                int   thri = __shfl(tib, 15);
                bool pass = (vb > thrv) || (vb == thrv && kidx < thri);
                unsigned long long mball = __ballot(pass);
                while (mball) {
                    int src = __ffsll(mball) - 1;
                    float vv = __shfl(vb, src);
                    int   ii = __shfl(kidx, src);
                    bool beat = (vv > tvb) || (vv == tvb && ii < tib);
                    float pv = __shfl_up(tvb, 1);
                    int   pi = __shfl_up(tib, 1);
                    bool beatp = (lane > 0) && ((vv > pv) || (vv == pv && ii < pi));
                    if (lane < 16 && beat) { tvb = beatp ? pv : vv; tib = beatp ? pi : ii; }
                    mball &= mball - 1;
                    if (mball) {
                        float t15 = __shfl(tvb, 15);
                        int   i15 = __shfl(tib, 15);
                        bool still = (vb > t15) || (vb == t15 && kidx < i15);
                        mball &= __ballot(still);
                    }
                }
            }
        }
    }

#pragma unroll
    for (int qq = 0; qq < 2; ++qq) {
        int qi = w * 2 + qq;
        float tv = qq ? tvb : tva;
        int   ti = qq ? tib : tia;
        if (qi < nq && lane < 16) {
            size_t o = (((size_t)b * LL + i0 + qi) * KB + kb) * TOPK + lane;
            tval2[o] = tv;
            tidx2[o] = ti;
        }
    }
}

__device__ __forceinline__ float gelu_f(float x) {
    return 0.5f * x * (1.0f + erff(x * 0.70710678118654752f));
}

// ---------------- kernel 7: merge(2x16) + blocked MLP GEMM + softmax + blend ----
__global__ __launch_bounds__(256, 4) void k_mlp2(const float* __restrict__ match,
        const float* __restrict__ qkf,
        const float* __restrict__ tval2, const int* __restrict__ tidx2,
        const int* __restrict__ qlist, const int* __restrict__ counts,
        const float* __restrict__ W1, const float* __restrict__ b1,
        const float* __restrict__ W2, const float* __restrict__ b2,
        float* __restrict__ out) {
    int b = blockIdx.y;
    int cnt = counts[b];
    int i0 = blockIdx.x * NQM;
    if (i0 >= cnt) return;
    int t = threadIdx.x;
    int ql = t >> 6;          // wave = query slot
    int lane = t & 63;
    int rt = lane >> 4;       // k-group (4 k's)
    int ht = lane & 15;       // h-group (8 h's)
    int h0 = ht * 8;
    int k0 = rt * 4;

    __shared__ float kf[64][KFP];    // 33.0 KB; rows 0..15 alias merge lists early
    __shared__ float tl[NQM][16];
    __shared__ int   tix[NQM][16];
    __shared__ float rr0[NQM][16], rr1[NQM][16];
    __shared__ int   qtok[NQM];
    __shared__ float qf[NQM][128];
    __shared__ float wgt[NQM][16];

    // alias merge buffers into kf (dead after rank-merge; kf staged after barrier)
    float (*mv)[32] = (float(*)[32])&kf[0][0];    // 128 floats
    int   (*mi)[32] = (int(*)[32])  &kf[8][0];    // 128 ints (disjoint rows)

    if (t < NQM) qtok[t] = qlist[b * LL + min(i0 + t, cnt - 1)];
    if (t < NQM * 32) {   // load KB=2 partial lists of 16 per query
        int q = t >> 5, u = t & 31;
        size_t o = (((size_t)b * LL + min(i0 + q, cnt - 1)) * KB + (u >> 4)) * TOPK + (u & 15);
        mv[q][u] = tval2[o];
        mi[q][u] = tidx2[o];
    }
    __syncthreads();
    if (t < NQM * 32) {   // exact (value desc, idx asc) rank over the 32 entries
        int q = t >> 5, u = t & 31;
        float v = mv[q][u]; int ii = mi[q][u];
        int rank = 0;
#pragma unroll 1
        for (int x = 0; x < 32; ++x) {
            float vx = mv[q][x]; int ix = mi[q][x];
            rank += ((vx > v) || (vx == v && (ix < ii || (ix == ii && x < u)))) ? 1 : 0;
        }
        if (rank < TOPK) {
            int kidx = (ii < 0 || ii >= LL) ? 0 : ii;
            tl[q][rank] = v;
            tix[q][rank] = kidx;
            int qt = qtok[q];
            rr0[q][rank] = (float)((kidx >> 6) - (qt >> 6)) * (1.0f / GG);
            rr1[q][rank] = (float)((kidx & 63) - (qt & 63)) * (1.0f / GG);
        }
    }
    __syncthreads();
    // stage qf + kf (overwrites the alias region -- merge results live in tl/tix)
    for (int idx = t; idx < NQM * 128; idx += 256) {
        int q = idx >> 7, d = idx & 127;
        qf[q][d] = qkf[((size_t)b * LL + qtok[q]) * DDIM + d];
    }
    for (int idx = t; idx < 64 * 128; idx += 256) {
        int row = idx >> 7, d = idx & 127;
        kf[row][d] = qkf[((size_t)b * LL + tix[row >> 4][row & 15]) * DDIM + 128 + d];
    }
    __syncthreads();

    // main GEMM: rows (q,k), cols h; thread = (q=ql, k0..k0+3, h0..h0+7)
    float acc[4][8];
#pragma unroll
    for (int i = 0; i < 4; ++i)
#pragma unroll
        for (int h = 0; h < 8; ++h) acc[i][h] = 0.f;

    const float4* W14 = (const float4*)W1;
    const float* qfr = qf[ql];
    const float* kfr0 = &kf[ql * 16 + k0][0];

    // software pipeline: W1 rows prefetched one j ahead
    float4 wa0 = W14[(0 * RHID + h0) >> 2];
    float4 wa1 = W14[((0 * RHID + h0) >> 2) + 1];
    float4 wb0 = W14[((RHID + 0) * RHID + h0) >> 2];
    float4 wb1 = W14[(((RHID + 0) * RHID + h0) >> 2) + 1];
    for (int j = 0; j < 128; ++j) {
        float4 cwa0 = wa0, cwa1 = wa1, cwb0 = wb0, cwb1 = wb1;
        if (j < 127) {
            int can = ((j + 1) * RHID + h0) >> 2;
            int cbn = ((RHID + j + 1) * RHID + h0) >> 2;
            wa0 = W14[can]; wa1 = W14[can + 1];
            wb0 = W14[cbn]; wb1 = W14[cbn + 1];
        }
        float qv = qfr[j];
#pragma unroll
        for (int i = 0; i < 4; ++i) {
            float kv = kfr0[i * KFP + j];
            float pa = qv * kv;
            float pb = fabsf(qv - kv);
            acc[i][0] += pa * cwa0.x + pb * cwb0.x;
            acc[i][1] += pa * cwa0.y + pb * cwb0.y;
            acc[i][2] += pa * cwa0.z + pb * cwb0.z;
            acc[i][3] += pa * cwa0.w + pb * cwb0.w;
            acc[i][4] += pa * cwa1.x + pb * cwb1.x;
            acc[i][5] += pa * cwa1.y + pb * cwb1.y;
            acc[i][6] += pa * cwa1.z + pb * cwb1.z;
            acc[i][7] += pa * cwa1.w + pb * cwb1.w;
        }
    }

    // tail rows + gelu + W2 dot
    int cl = (256 * RHID + h0) >> 2;
    int cr0 = (257 * RHID + h0) >> 2;
    int cr1 = (258 * RHID + h0) >> 2;
    float4 wl0 = W14[cl], wl1 = W14[cl + 1];
    float4 wra = W14[cr0], wrb = W14[cr0 + 1];
    float4 wsa = W14[cr1], wsb = W14[cr1 + 1];
    float4 bb0 = ((const float4*)b1)[h0 >> 2], bb1v = ((const float4*)b1)[(h0 >> 2) + 1];
    float4 w20 = ((const float4*)W2)[h0 >> 2], w21 = ((const float4*)W2)[(h0 >> 2) + 1];
    float b2v = b2[0];

    float scv0, scv1, scv2, scv3;
    {
#pragma unroll
        for (int i = 0; i < 4; ++i) {
            int k = k0 + i;
            float tlv = tl[ql][k], r0v = rr0[ql][k], r1v = rr1[ql][k];
            float s = 0.f;
            s += gelu_f(acc[i][0] + tlv*wl0.x + r0v*wra.x + r1v*wsa.x + bb0.x) * w20.x;
            s += gelu_f(acc[i][1] + tlv*wl0.y + r0v*wra.y + r1v*wsa.y + bb0.y) * w20.y;
            s += gelu_f(acc[i][2] + tlv*wl0.z + r0v*wra.z + r1v*wsa.z + bb0.z) * w20.z;
            s += gelu_f(acc[i][3] + tlv*wl0.w + r0v*wra.w + r1v*wsa.w + bb0.w) * w20.w;
            s += gelu_f(acc[i][4] + tlv*wl1.x + r0v*wrb.x + r1v*wsb.x + bb1v.x) * w21.x;
            s += gelu_f(acc[i][5] + tlv*wl1.y + r0v*wrb.y + r1v*wsb.y + bb1v.y) * w21.y;
            s += gelu_f(acc[i][6] + tlv*wl1.z + r0v*wrb.z + r1v*wsb.z + bb1v.z) * w21.z;
            s += gelu_f(acc[i][7] + tlv*wl1.w + r0v*wrb.w + r1v*wsb.w + bb1v.w) * w21.w;
            // reduce over the 16 ht lanes (xor on low 4 bits stays in-group)
            s += __shfl_xor(s, 1); s += __shfl_xor(s, 2);
            s += __shfl_xor(s, 4); s += __shfl_xor(s, 8);
            if (i == 0) scv0 = s; else if (i == 1) scv1 = s;
            else if (i == 2) scv2 = s; else scv3 = s;
        }
    }
    if (ht == 0) {
        wgt[ql][k0 + 0] = scv0;
        wgt[ql][k0 + 1] = scv1;
        wgt[ql][k0 + 2] = scv2;
        wgt[ql][k0 + 3] = scv3;
    }
    __syncthreads();
    if (lane < 16) {
        float refined = tl[ql][lane] + wgt[ql][lane] + b2v;
        float m = refined;
        for (int off = 8; off > 0; off >>= 1) m = fmaxf(m, __shfl_xor(m, off, 16));
        float e = expf(refined - m);
        float s = e;
        for (int off = 8; off > 0; off >>= 1) s += __shfl_xor(s, off, 16);
        wgt[ql][lane] = e / s;
    }
    __syncthreads();
    // blend + scatter (wave per query)
    int gyq = qtok[ql] >> 6, gxq = qtok[ql] & 63;
    for (int p = lane; p < PDIM; p += 64) {
        float o = 0.f;
#pragma unroll
        for (int k = 0; k < TOPK; ++k)
            o += wgt[ql][k] * match[((size_t)b * LL + tix[ql][k]) * MDIM + p];
        int c = p >> 6, ky = (p >> 3) & 7, kx = p & 7;
        out[((b * CC + c) * HH + gyq * 8 + ky) * WW + gxq * 8 + kx] = o;
    }
}

// ---------------- launch ----------------
extern "C" void kernel_launch(void* const* d_in, const int* in_sizes, int n_in,
                              void* d_out, int out_size, void* d_ws, size_t ws_size,
                              hipStream_t stream) {
    const float* image    = (const float*)d_in[0];
    const float* features = (const float*)d_in[1];
    const int*   tmask    = (const int*)d_in[2];
    const float* W_desc   = (const float*)d_in[3];
    const float* Wq       = (const float*)d_in[4];
    const float* Wk       = (const float*)d_in[5];
    const float* W1       = (const float*)d_in[6];
    const float* b1       = (const float*)d_in[7];
    const float* W2       = (const float*)d_in[8];
    const float* b2       = (const float*)d_in[9];
    float* out = (float*)d_out;

    float* ws    = (float*)d_ws;
    float* match = ws;                                      // B*L*320
    float* desc  = match + (size_t)BB * LL * MDIM;          // B*L*256
    float* qkf   = desc  + (size_t)BB * LL * DDIM;          // B*L*256
    float* kdt   = qkf   + (size_t)BB * LL * DDIM;          // B*256*L (transposed)
    float* tval2 = kdt   + (size_t)BB * DDIM * LL;          // B*L*KB*16
    int*   tidx2 = (int*)(tval2 + (size_t)BB * LL * KB * TOPK); // B*L*KB*16
    int*   qlist = tidx2 + (size_t)BB * LL * KB * TOPK;     // B*L
    int*   klist = qlist + BB * LL;                         // B*L
    int*   counts = klist + BB * LL;                        // 2*B

    hipMemsetAsync(counts, 0, 2 * BB * sizeof(int), stream);
    k_build2<<<dim3(LL / 64, BB), 256, 0, stream>>>(image, features, match, out);
    k_compact<<<(BB * LL + 255) / 256, 256, 0, stream>>>(tmask, qlist, klist, counts);
    k_gemm2<<<BB * LL / TOKG, 256, 0, stream>>>(match, W_desc, Wq, Wk, desc, qkf);
    k_gatherkT<<<dim3(LL / TKT, BB), 256, 0, stream>>>(desc, klist, counts, kdt);
    k_topk4<<<dim3(LL / NQ2, KB, BB), 256, 0, stream>>>(desc, kdt, qlist, klist,
                                                        counts, tval2, tidx2);
    k_mlp2<<<dim3(LL / NQM, BB), 256, 0, stream>>>(match, qkf, tval2, tidx2, qlist,
                                                   counts, W1, b1, W2, b2, out);
}

// Round 22
// 402.978 us; speedup vs baseline: 1.0940x; 1.0940x over previous
//
#include <hip/hip_runtime.h>
#include <hip/hip_bf16.h>
#include <math.h>

// Problem constants
#define BB 2
#define CC 3
#define HH 512
#define WW 512
#define GG 64
#define LL 4096
#define FDIM 128
#define PDIM 192   // C*K*K
#define MDIM 320   // PDIM + FDIM
#define DDIM 256
#define TOPK 16
#define RHID 128
#define SCALE (1.0f/16.0f)   // 1/(sqrt(256)*TEMP)

#define NQ2 8      // queries per topk block
#define CHK3 1024  // key chunk (4 contiguous keys per thread, 256 threads)
#define KB 2       // key partials
#define TOKG 16    // tokens per gemm block
#define TKT 32     // keys per transpose-gather block
#define NQM 4      // queries per mlp block
#define KFP 129    // kf row stride (odd: conflict-free)

// ---------------- kernel 2: fused build (img rows + out copy + feat transpose) ----
__global__ __launch_bounds__(256) void k_build2(const float* __restrict__ img,
        const float* __restrict__ feat, float* __restrict__ match,
        float* __restrict__ out) {
    int b = blockIdx.y;
    int l0 = blockIdx.x * 64;         // tokens l0..l0+63, gy = l0>>6
    int gy = l0 >> 6;
    int t = threadIdx.x;

    const float4* im4 = (const float4*)img;
    float4* out4 = (float4*)out;
    for (int idx = t; idx < 24 * 128; idx += 256) {   // 128 float4 per row
        int r = idx >> 7;             // 0..23 = c*8+ky
        int x4 = idx & 127;
        int c = r >> 3, ky = r & 7;
        size_t gofs = (((size_t)(b * CC + c) * HH + gy * 8 + ky) * WW >> 2) + x4;
        float4 v = im4[gofs];
        out4[gofs] = v;               // fused baseline copy
        int gx = x4 >> 1;
        int kx = (x4 & 1) * 4;
        *(float4*)&match[(size_t)(b * LL + l0 + gx) * MDIM + c * 64 + ky * 8 + kx] = v;
    }

    __shared__ float tf[FDIM][65];    // padded: conflict-free transpose
    for (int idx = t; idx < FDIM * 64; idx += 256) {
        int f = idx >> 6, ll = idx & 63;
        tf[f][ll] = feat[((size_t)(b * FDIM + f) << 12) + l0 + ll];
    }
    __syncthreads();
    for (int idx = t; idx < 64 * FDIM; idx += 256) {
        int ll = idx >> 7, f = idx & 127;
        match[(size_t)(b * LL + l0 + ll) * MDIM + PDIM + f] = tf[f][ll];
    }
}

// ---------------- kernel 3: compact masked queries AND valid keys ----------------
__global__ void k_compact(const int* __restrict__ mask, int* __restrict__ qlist,
                          int* __restrict__ klist, int* __restrict__ counts) {
    int bl = blockIdx.x * blockDim.x + threadIdx.x;
    if (bl >= BB * LL) return;
    int b = bl >> 12, l = bl & (LL - 1);
    if (mask[bl] > 0) {
        int s = atomicAdd(&counts[b], 1);          // qcnt
        qlist[b * LL + s] = l;
    } else {
        int s = atomicAdd(&counts[BB + b], 1);     // kcnt
        klist[b * LL + s] = l;
    }
}

// ---------------- kernel 4: fused token GEMM (desc + [qf|kf]), TOKG=16 ----------
__global__ __launch_bounds__(256) void k_gemm2(const float* __restrict__ match,
        const float* __restrict__ Wd, const float* __restrict__ Wq,
        const float* __restrict__ Wk,
        float* __restrict__ desc, float* __restrict__ qkf) {
    __shared__ float sm[TOKG * MDIM];   // 20 KB
    int base = blockIdx.x * TOKG;
    int t = threadIdx.x;
    for (int i = t; i < TOKG * MDIM; i += 256) sm[i] = match[(size_t)base * MDIM + i];
    __syncthreads();
    const float4* sm4 = (const float4*)sm;
    const float* W1p = (t < 128) ? Wq : Wk;
    int c1 = t & 127;
    float acc0[TOKG], acc1[TOKG];
#pragma unroll
    for (int tt = 0; tt < TOKG; ++tt) { acc0[tt] = 0.f; acc1[tt] = 0.f; }
    for (int m = 0; m < MDIM; m += 4) {
        float w00 = Wd[(m+0)*DDIM + t], w01 = Wd[(m+1)*DDIM + t];
        float w02 = Wd[(m+2)*DDIM + t], w03 = Wd[(m+3)*DDIM + t];
        float w10 = W1p[(m+0)*RHID + c1], w11 = W1p[(m+1)*RHID + c1];
        float w12 = W1p[(m+2)*RHID + c1], w13 = W1p[(m+3)*RHID + c1];
        int mg = m >> 2;
#pragma unroll
        for (int tt = 0; tt < TOKG; ++tt) {
            float4 s = sm4[tt * (MDIM/4) + mg];
            acc0[tt] += s.x*w00 + s.y*w01 + s.z*w02 + s.w*w03;
            acc1[tt] += s.x*w10 + s.y*w11 + s.z*w12 + s.w*w13;
        }
    }
#pragma unroll
    for (int tt = 0; tt < TOKG; ++tt) {
        desc[(size_t)(base+tt)*DDIM + t] = acc0[tt];
        qkf [(size_t)(base+tt)*DDIM + t] = acc1[tt];
    }
}

// ---------------- kernel 5: gather valid keys, TRANSPOSED: kdesc_t[d][kk] ----
__global__ __launch_bounds__(256) void k_gatherkT(const float* __restrict__ desc,
        const int* __restrict__ klist, const int* __restrict__ counts,
        float* __restrict__ kdesc_t) {
    int b = blockIdx.y;
    int vcnt = counts[BB + b];
    int kt = blockIdx.x * TKT;
    if (kt >= vcnt) return;
    int nk = min(TKT, vcnt - kt);
    __shared__ float sm[TKT][DDIM + 1];   // +1 pad: transpose-read conflict-free
    int t = threadIdx.x;
    for (int r = (t >> 6); r < nk; r += 4) {
        int src = klist[b * LL + kt + r];
        const float4* s = (const float4*)(desc + ((size_t)b * LL + src) * DDIM);
        float4 v = s[t & 63];
        int d0 = (t & 63) * 4;
        sm[r][d0] = v.x; sm[r][d0+1] = v.y; sm[r][d0+2] = v.z; sm[r][d0+3] = v.w;
    }
    __syncthreads();
    float* outb = kdesc_t + (size_t)b * DDIM * LL;
    int kk = t & 31;
    for (int d = (t >> 5); d < DDIM; d += 8) {
        if (kk < nk) outb[(size_t)d * LL + kt + kk] = sm[kk][d];
    }
}

// ---------------- kernel 6: fused logits + wave-register top-16 (r13 champion) ----
__global__ __launch_bounds__(256, 4) void k_topk4(const float* __restrict__ desc,
        const float* __restrict__ kdt,
        const int* __restrict__ qlist, const int* __restrict__ klist,
        const int* __restrict__ counts,
        float* __restrict__ tval2, int* __restrict__ tidx2) {
    int b = blockIdx.z;
    int kb = blockIdx.y;
    int cnt  = counts[b];
    int vcnt = counts[BB + b];
    int i0 = blockIdx.x * NQ2;
    if (i0 >= cnt) return;
    int nq = min(NQ2, cnt - i0);
    int t = threadIdx.x;
    int lane = t & 63, w = t >> 6;

    __shared__ float sq[NQ2 * DDIM];     // 8 KB
    __shared__ float lc[NQ2][CHK3];      // 32 KB  (40 KB total -> 4 blocks/CU)

#pragma unroll
    for (int qi = 0; qi < NQ2; ++qi) {
        int qtok = qlist[b * LL + i0 + min(qi, nq - 1)];
        sq[qi * DDIM + t] = desc[((size_t)b * LL + qtok) * DDIM + t];
    }
    __syncthreads();

    int khalf = (vcnt + 1) >> 1;
    int kstart = kb * khalf;
    int kend = min(vcnt, kstart + khalf);

    float tva = -INFINITY, tvb = -INFINITY;
    int   tia = 0x7fffffff, tib = 0x7fffffff;

    const float4* sq4 = (const float4*)sq;
    const float* kbase = kdt + (size_t)b * DDIM * LL;
    const int* klb = klist + b * LL;

    int nch = (kend > kstart) ? (kend - kstart + CHK3 - 1) / CHK3 : 0;
    for (int ch = 0; ch < nch; ++ch) {
        int base = kstart + ch * CHK3;
        int k0 = base + 4 * t;            // 4 contiguous keys
        int k0c = min(k0, LL - 4);        // stay inside the d-row

        float acc[NQ2][4];
#pragma unroll
        for (int qi = 0; qi < NQ2; ++qi)
#pragma unroll
            for (int r = 0; r < 4; ++r) acc[qi][r] = 0.f;

#pragma unroll 2
        for (int db = 0; db < DDIM / 4; ++db) {
            float4 qv[NQ2];
#pragma unroll
            for (int qi = 0; qi < NQ2; ++qi) qv[qi] = sq4[qi * (DDIM/4) + db];
#pragma unroll
            for (int dd = 0; dd < 4; ++dd) {
                float4 kx = *(const float4*)(kbase + (size_t)(db * 4 + dd) * LL + k0c);
#pragma unroll
                for (int qi = 0; qi < NQ2; ++qi) {
                    float sv = (dd == 0) ? qv[qi].x : (dd == 1) ? qv[qi].y
                             : (dd == 2) ? qv[qi].z : qv[qi].w;
                    acc[qi][0] += sv * kx.x;
                    acc[qi][1] += sv * kx.y;
                    acc[qi][2] += sv * kx.z;
                    acc[qi][3] += sv * kx.w;
                }
            }
        }
        __syncthreads();   // previous selection done reading lc
#pragma unroll
        for (int qi = 0; qi < NQ2; ++qi) {
            float4 o;
            o.x = (k0 + 0 < kend) ? acc[qi][0] * SCALE : -INFINITY;
            o.y = (k0 + 1 < kend) ? acc[qi][1] * SCALE : -INFINITY;
            o.z = (k0 + 2 < kend) ? acc[qi][2] * SCALE : -INFINITY;
            o.w = (k0 + 3 < kend) ? acc[qi][3] * SCALE : -INFINITY;
            *(float4*)&lc[qi][4 * t] = o;
        }
        __syncthreads();

        // merged selection: one pass over j-groups; klist loaded once, both
        // queries (2w, 2w+1) processed from the same loads (r13-proven).
        for (int j = 0; j < CHK3 / 64; ++j) {
            int p = j * 64 + lane;
            int gk = base + p;
            int kidx = (gk < kend) ? klb[gk] : 0x7fffffff;
            float va = lc[2 * w + 0][p];
            float vb = lc[2 * w + 1][p];
            {   // query A
                float thrv = __shfl(tva, 15);
                int   thri = __shfl(tia, 15);
                bool pass = (va > thrv) || (va == thrv && kidx < thri);
                unsigned long long mball = __ballot(pass);
                while (mball) {
                    int src = __ffsll(mball) - 1;
                    float vv = __shfl(va, src);
                    int   ii = __shfl(kidx, src);
                    bool beat = (vv > tva) || (vv == tva && ii < tia);
                    float pv = __shfl_up(tva, 1);
                    int   pi = __shfl_up(tia, 1);
                    bool beatp = (lane > 0) && ((vv > pv) || (vv == pv && ii < pi));
                    if (lane < 16 && beat) { tva = beatp ? pv : vv; tia = beatp ? pi : ii; }
                    mball &= mball - 1;
                    if (mball) {
                        float t15 = __shfl(tva, 15);
                        int   i15 = __shfl(tia, 15);
                        bool still = (va > t15) || (va == t15 && kidx < i15);
                        mball &= __ballot(still);
                    }
                }
            }
            {   // query B
                float thrv = __shfl(tvb, 15);
                int   thri = __shfl(tib, 15);
                bool pass = (vb > thrv) || (vb == thrv && kidx < thri);
                unsigned long long mball = __ballot(pass);
                while (mball) {
                    int src = __ffsll(mball) - 1;
                    float vv = __shfl(vb, src);
                    int   ii = __shfl(kidx, src);
                    bool beat = (vv > tvb) || (vv == tvb && ii < tib);
                    float pv = __shfl_up(tvb, 1);
                    int   pi = __shfl_up(tib, 1);
                    bool beatp = (lane > 0) && ((vv > pv) || (vv == pv && ii < pi));
                    if (lane < 16 && beat) { tvb = beatp ? pv : vv; tib = beatp ? pi : ii; }
                    mball &= mball - 1;
                    if (mball) {
                        float t15 = __shfl(tvb, 15);
                        int   i15 = __shfl(tib, 15);
                        bool still = (vb > t15) || (vb == t15 && kidx < i15);
                        mball &= __ballot(still);
                    }
                }
            }
        }
    }

#pragma unroll
    for (int qq = 0; qq < 2; ++qq) {
        int qi = w * 2 + qq;
        float tv = qq ? tvb : tva;
        int   ti = qq ? tib : tia;
        if (qi < nq && lane < 16) {
            size_t o = (((size_t)b * LL + i0 + qi) * KB + kb) * TOPK + lane;
            tval2[o] = tv;
            tidx2[o] = ti;
        }
    }
}

__device__ __forceinline__ float gelu_f(float x) {
    return 0.5f * x * (1.0f + erff(x * 0.70710678118654752f));
}

// ---------------- kernel 7: merge(2x16) + blocked MLP GEMM + softmax + blend ----
// j-loop software-pipelined: W1 rows for j+1 loaded while computing j.
__global__ __launch_bounds__(256, 4) void k_mlp2(const float* __restrict__ match,
        const float* __restrict__ qkf,
        const float* __restrict__ tval2, const int* __restrict__ tidx2,
        const int* __restrict__ qlist, const int* __restrict__ counts,
        const float* __restrict__ W1, const float* __restrict__ b1,
        const float* __restrict__ W2, const float* __restrict__ b2,
        float* __restrict__ out) {
    int b = blockIdx.y;
    int cnt = counts[b];
    int i0 = blockIdx.x * NQM;
    if (i0 >= cnt) return;
    int t = threadIdx.x;
    int ql = t >> 6;          // wave = query slot
    int lane = t & 63;
    int rt = lane >> 4;       // k-group (4 k's)
    int ht = lane & 15;       // h-group (8 h's)
    int h0 = ht * 8;
    int k0 = rt * 4;

    __shared__ float kf[64][KFP];    // 33.0 KB; rows 0..15 alias merge lists early
    __shared__ float tl[NQM][16];
    __shared__ int   tix[NQM][16];
    __shared__ float rr0[NQM][16], rr1[NQM][16];
    __shared__ int   qtok[NQM];
    __shared__ float qf[NQM][128];
    __shared__ float wgt[NQM][16];

    // alias merge buffers into kf (dead after rank-merge; kf staged after barrier)
    float (*mv)[32] = (float(*)[32])&kf[0][0];    // 128 floats
    int   (*mi)[32] = (int(*)[32])  &kf[8][0];    // 128 ints (disjoint rows)

    if (t < NQM) qtok[t] = qlist[b * LL + min(i0 + t, cnt - 1)];
    if (t < NQM * 32) {   // load KB=2 partial lists of 16 per query
        int q = t >> 5, u = t & 31;
        size_t o = (((size_t)b * LL + min(i0 + q, cnt - 1)) * KB + (u >> 4)) * TOPK + (u & 15);
        mv[q][u] = tval2[o];
        mi[q][u] = tidx2[o];
    }
    __syncthreads();
    if (t < NQM * 32) {   // exact (value desc, idx asc) rank over the 32 entries
        int q = t >> 5, u = t & 31;
        float v = mv[q][u]; int ii = mi[q][u];
        int rank = 0;
#pragma unroll 1
        for (int x = 0; x < 32; ++x) {
            float vx = mv[q][x]; int ix = mi[q][x];
            rank += ((vx > v) || (vx == v && (ix < ii || (ix == ii && x < u)))) ? 1 : 0;
        }
        if (rank < TOPK) {
            int kidx = (ii < 0 || ii >= LL) ? 0 : ii;
            tl[q][rank] = v;
            tix[q][rank] = kidx;
            int qt = qtok[q];
            rr0[q][rank] = (float)((kidx >> 6) - (qt >> 6)) * (1.0f / GG);
            rr1[q][rank] = (float)((kidx & 63) - (qt & 63)) * (1.0f / GG);
        }
    }
    __syncthreads();
    // stage qf + kf (overwrites the alias region -- merge results live in tl/tix)
    for (int idx = t; idx < NQM * 128; idx += 256) {
        int q = idx >> 7, d = idx & 127;
        qf[q][d] = qkf[((size_t)b * LL + qtok[q]) * DDIM + d];
    }
    for (int idx = t; idx < 64 * 128; idx += 256) {
        int row = idx >> 7, d = idx & 127;
        kf[row][d] = qkf[((size_t)b * LL + tix[row >> 4][row & 15]) * DDIM + 128 + d];
    }
    __syncthreads();

    // main GEMM: rows (q,k), cols h; thread = (q=ql, k0..k0+3, h0..h0+7)
    float acc[4][8];
#pragma unroll
    for (int i = 0; i < 4; ++i)
#pragma unroll
        for (int h = 0; h < 8; ++h) acc[i][h] = 0.f;

    const float4* W14 = (const float4*)W1;
    const float* qfr = qf[ql];
    const float* kfr0 = &kf[ql * 16 + k0][0];

    // software pipeline: W1 rows prefetched one j ahead
    float4 wa0 = W14[(0 * RHID + h0) >> 2];
    float4 wa1 = W14[((0 * RHID + h0) >> 2) + 1];
    float4 wb0 = W14[((RHID + 0) * RHID + h0) >> 2];
    float4 wb1 = W14[(((RHID + 0) * RHID + h0) >> 2) + 1];
    for (int j = 0; j < 128; ++j) {
        float4 cwa0 = wa0, cwa1 = wa1, cwb0 = wb0, cwb1 = wb1;
        if (j < 127) {
            int can = ((j + 1) * RHID + h0) >> 2;
            int cbn = ((RHID + j + 1) * RHID + h0) >> 2;
            wa0 = W14[can]; wa1 = W14[can + 1];
            wb0 = W14[cbn]; wb1 = W14[cbn + 1];
        }
        float qv = qfr[j];
#pragma unroll
        for (int i = 0; i < 4; ++i) {
            float kv = kfr0[i * KFP + j];
            float pa = qv * kv;
            float pb = fabsf(qv - kv);
            acc[i][0] += pa * cwa0.x + pb * cwb0.x;
            acc[i][1] += pa * cwa0.y + pb * cwb0.y;
            acc[i][2] += pa * cwa0.z + pb * cwb0.z;
            acc[i][3] += pa * cwa0.w + pb * cwb0.w;
            acc[i][4] += pa * cwa1.x + pb * cwb1.x;
            acc[i][5] += pa * cwa1.y + pb * cwb1.y;
            acc[i][6] += pa * cwa1.z + pb * cwb1.z;
            acc[i][7] += pa * cwa1.w + pb * cwb1.w;
        }
    }

    // tail rows + gelu + W2 dot
    int cl = (256 * RHID + h0) >> 2;
    int cr0 = (257 * RHID + h0) >> 2;
    int cr1 = (258 * RHID + h0) >> 2;
    float4 wl0 = W14[cl], wl1 = W14[cl + 1];
    float4 wra = W14[cr0], wrb = W14[cr0 + 1];
    float4 wsa = W14[cr1], wsb = W14[cr1 + 1];
    float4 bb0 = ((const float4*)b1)[h0 >> 2], bb1v = ((const float4*)b1)[(h0 >> 2) + 1];
    float4 w20 = ((const float4*)W2)[h0 >> 2], w21 = ((const float4*)W2)[(h0 >> 2) + 1];
    float b2v = b2[0];

    float scv0, scv1, scv2, scv3;
    {
#pragma unroll
        for (int i = 0; i < 4; ++i) {
            int k = k0 + i;
            float tlv = tl[ql][k], r0v = rr0[ql][k], r1v = rr1[ql][k];
            float s = 0.f;
            s += gelu_f(acc[i][0] + tlv*wl0.x + r0v*wra.x + r1v*wsa.x + bb0.x) * w20.x;
            s += gelu_f(acc[i][1] + tlv*wl0.y + r0v*wra.y + r1v*wsa.y + bb0.y) * w20.y;
            s += gelu_f(acc[i][2] + tlv*wl0.z + r0v*wra.z + r1v*wsa.z + bb0.z) * w20.z;
            s += gelu_f(acc[i][3] + tlv*wl0.w + r0v*wra.w + r1v*wsa.w + bb0.w) * w20.w;
            s += gelu_f(acc[i][4] + tlv*wl1.x + r0v*wrb.x + r1v*wsb.x + bb1v.x) * w21.x;
            s += gelu_f(acc[i][5] + tlv*wl1.y + r0v*wrb.y + r1v*wsb.y + bb1v.y) * w21.y;
            s += gelu_f(acc[i][6] + tlv*wl1.z + r0v*wrb.z + r1v*wsb.z + bb1v.z) * w21.z;
            s += gelu_f(acc[i][7] + tlv*wl1.w + r0v*wrb.w + r1v*wsb.w + bb1v.w) * w21.w;
            // reduce over the 16 ht lanes (xor on low 4 bits stays in-group)
            s += __shfl_xor(s, 1); s += __shfl_xor(s, 2);
            s += __shfl_xor(s, 4); s += __shfl_xor(s, 8);
            if (i == 0) scv0 = s; else if (i == 1) scv1 = s;
            else if (i == 2) scv2 = s; else scv3 = s;
        }
    }
    if (ht == 0) {
        wgt[ql][k0 + 0] = scv0;
        wgt[ql][k0 + 1] = scv1;
        wgt[ql][k0 + 2] = scv2;
        wgt[ql][k0 + 3] = scv3;
    }
    __syncthreads();
    if (lane < 16) {
        float refined = tl[ql][lane] + wgt[ql][lane] + b2v;
        float m = refined;
        for (int off = 8; off > 0; off >>= 1) m = fmaxf(m, __shfl_xor(m, off, 16));
        float e = expf(refined - m);
        float s = e;
        for (int off = 8; off > 0; off >>= 1) s += __shfl_xor(s, off, 16);
        wgt[ql][lane] = e / s;
    }
    __syncthreads();
    // blend + scatter (wave per query)
    int gyq = qtok[ql] >> 6, gxq = qtok[ql] & 63;
    for (int p = lane; p < PDIM; p += 64) {
        float o = 0.f;
#pragma unroll
        for (int k = 0; k < TOPK; ++k)
            o += wgt[ql][k] * match[((size_t)b * LL + tix[ql][k]) * MDIM + p];
        int c = p >> 6, ky = (p >> 3) & 7, kx = p & 7;
        out[((b * CC + c) * HH + gyq * 8 + ky) * WW + gxq * 8 + kx] = o;
    }
}

// ---------------- launch ----------------
extern "C" void kernel_launch(void* const* d_in, const int* in_sizes, int n_in,
                              void* d_out, int out_size, void* d_ws, size_t ws_size,
                              hipStream_t stream) {
    const float* image    = (const float*)d_in[0];
    const float* features = (const float*)d_in[1];
    const int*   tmask    = (const int*)d_in[2];
    const float* W_desc   = (const float*)d_in[3];
    const float* Wq       = (const float*)d_in[4];
    const float* Wk       = (const float*)d_in[5];
    const float* W1       = (const float*)d_in[6];
    const float* b1       = (const float*)d_in[7];
    const float* W2       = (const float*)d_in[8];
    const float* b2       = (const float*)d_in[9];
    float* out = (float*)d_out;

    float* ws    = (float*)d_ws;
    float* match = ws;                                      // B*L*320
    float* desc  = match + (size_t)BB * LL * MDIM;          // B*L*256
    float* qkf   = desc  + (size_t)BB * LL * DDIM;          // B*L*256
    float* kdt   = qkf   + (size_t)BB * LL * DDIM;          // B*256*L (transposed)
    float* tval2 = kdt   + (size_t)BB * DDIM * LL;          // B*L*KB*16
    int*   tidx2 = (int*)(tval2 + (size_t)BB * LL * KB * TOPK); // B*L*KB*16
    int*   qlist = tidx2 + (size_t)BB * LL * KB * TOPK;     // B*L
    int*   klist = qlist + BB * LL;                         // B*L
    int*   counts = klist + BB * LL;                        // 2*B

    hipMemsetAsync(counts, 0, 2 * BB * sizeof(int), stream);
    k_build2<<<dim3(LL / 64, BB), 256, 0, stream>>>(image, features, match, out);
    k_compact<<<(BB * LL + 255) / 256, 256, 0, stream>>>(tmask, qlist, klist, counts);
    k_gemm2<<<BB * LL / TOKG, 256, 0, stream>>>(match, W_desc, Wq, Wk, desc, qkf);
    k_gatherkT<<<dim3(LL / TKT, BB), 256, 0, stream>>>(desc, klist, counts, kdt);
    k_topk4<<<dim3(LL / NQ2, KB, BB), 256, 0, stream>>>(desc, kdt, qlist, klist,
                                                        counts, tval2, tidx2);
    k_mlp2<<<dim3(LL / NQM, BB), 256, 0, stream>>>(match, qkf, tval2, tidx2, qlist,
                                                   counts, W1, b1, W2, b2, out);
}